// Round 4
// baseline (652.080 us; speedup 1.0000x reference)
//
#include <hip/hip_runtime.h>
#include <hip/hip_bf16.h>
#include <stdint.h>

// RandLinear: out[n,o] = sum_i x[n,i] * (mu_w[o,i] + exp(ls_w[o,i])*eps_w[o,i]) + bias[o]
// bf16 materialization + 256x256 GEMM-BT, m201-style 4-phase/K-tile (BK=64)
// lagged-read pipeline, 2-buffer LDS (128 KiB), counted vmcnt, XOR swizzle,
// setprio MFMA clusters, XCD-chunked block swizzle.
//
// Per K-tile T (buf p=T&1), phases (each: reads | stage | barrier | MFMA | barrier):
//  P1: read a03(T) [8 ds];  stage A-bot(T+1);  MFMA Q10(T-1) = aHi x bLo
//  P2: read b01(T) [4 ds];  stage B-top(T+1);  MFMA Q11(T-1) = aHi x bHi
//  P3: read b23+a47(T) [12];stage B-bot(T+1);  MFMA Q00(T)   = aLo x bLo
//  P4: (no reads);          stage A-top(T+2);  MFMA Q01(T)   = aLo x bHi; vmcnt(2)
// vmcnt(2) at P4(T) forces ht1..ht4(T+1) landed (only the newest stage remains
// in flight) -> tile T+1 fully resident at its P1; pipeline never drains to 0.
// Liveness: aLo(T):P1->P3,P4; bLo(T):P2->P3,P1(T+1); aHi,bHi(T):P3->P4..P2(T+1).
// All single-set: acc128 + aLo32 + aHi32 + bLo16 + bHi16 = 224 VGPR core.

constexpr int M    = 8192;  // rows of x ("N" in reference)
constexpr int K    = 4096;  // IN
constexpr int NOUT = 4096;  // OUT

typedef __bf16 bf16x8 __attribute__((ext_vector_type(8)));
typedef float  f32x4  __attribute__((ext_vector_type(4)));
typedef short  short8 __attribute__((ext_vector_type(8)));

#define DI __device__ __forceinline__

DI void gl_lds16(const void* g, void* l) {
  __builtin_amdgcn_global_load_lds(
      (__attribute__((address_space(1))) void*)(g),
      (__attribute__((address_space(3))) void*)(l),
      16, 0, 0);
}

union BF8 {
  __hip_bfloat16 h[8];
  short8 s;
};

// ---- fused prep: [0,XBLK) cast x; [XBLK,XBLK+WBLK) fuse W; tail: bias ----
constexpr int XBLK = (M * K / 8) / 256;        // 16384
constexpr int WBLK = (NOUT * K / 8) / 256;     // 8192
constexpr int BBLK = (NOUT + 255) / 256;       // 16

__global__ __launch_bounds__(256) void prep_kernel(
    const float* __restrict__ x, short* __restrict__ xb,
    const float* __restrict__ mu, const float* __restrict__ ls,
    const float* __restrict__ eps, short* __restrict__ wb,
    const float* __restrict__ mu_b, const float* __restrict__ ls_b,
    const float* __restrict__ eps_b, float* __restrict__ bias) {
  const int b = blockIdx.x;
  if (b < XBLK) {
    int i = b * 256 + threadIdx.x;
    const float4* src = (const float4*)x;
    float4 f0 = src[2 * i + 0];
    float4 f1 = src[2 * i + 1];
    BF8 u;
    u.h[0] = __float2bfloat16(f0.x);
    u.h[1] = __float2bfloat16(f0.y);
    u.h[2] = __float2bfloat16(f0.z);
    u.h[3] = __float2bfloat16(f0.w);
    u.h[4] = __float2bfloat16(f1.x);
    u.h[5] = __float2bfloat16(f1.y);
    u.h[6] = __float2bfloat16(f1.z);
    u.h[7] = __float2bfloat16(f1.w);
    ((short8*)xb)[i] = u.s;
  } else if (b < XBLK + WBLK) {
    int i = (b - XBLK) * 256 + threadIdx.x;
    const float4* mu4 = (const float4*)mu;
    const float4* ls4 = (const float4*)ls;
    const float4* ep4 = (const float4*)eps;
    float4 m0 = mu4[2 * i + 0], m1 = mu4[2 * i + 1];
    float4 l0 = ls4[2 * i + 0], l1 = ls4[2 * i + 1];
    float4 e0 = ep4[2 * i + 0], e1 = ep4[2 * i + 1];
    BF8 u;
    u.h[0] = __float2bfloat16(m0.x + __expf(l0.x) * e0.x);
    u.h[1] = __float2bfloat16(m0.y + __expf(l0.y) * e0.y);
    u.h[2] = __float2bfloat16(m0.z + __expf(l0.z) * e0.z);
    u.h[3] = __float2bfloat16(m0.w + __expf(l0.w) * e0.w);
    u.h[4] = __float2bfloat16(m1.x + __expf(l1.x) * e1.x);
    u.h[5] = __float2bfloat16(m1.y + __expf(l1.y) * e1.y);
    u.h[6] = __float2bfloat16(m1.z + __expf(l1.z) * e1.z);
    u.h[7] = __float2bfloat16(m1.w + __expf(l1.w) * e1.w);
    ((short8*)wb)[i] = u.s;
  } else {
    int i = (b - XBLK - WBLK) * 256 + threadIdx.x;
    if (i < NOUT) bias[i] = mu_b[i] + expf(ls_b[i]) * eps_b[i];
  }
}

// ---- GEMM: C[m,n] = sum_k A[m,k]*B[n,k] + bias[n] ----
constexpr int BM = 256, BN = 256, BK = 64;
constexpr int NT = K / BK;  // 64 K-tiles

__global__ __launch_bounds__(512, 2) void gemm_bt_kernel(const short* __restrict__ A,
                                                         const short* __restrict__ B,
                                                         const float* __restrict__ bias,
                                                         float* __restrict__ C) {
  // [buf][half][128 rows x 64 k] bf16 = 16 KiB per half; total 128 KiB.
  __shared__ __align__(16) short Alds[2][2][128 * 64];
  __shared__ __align__(16) short Blds[2][2][128 * 64];

  const int tid  = threadIdx.x;
  const int lane = tid & 63;
  const int wave = tid >> 6;   // 0..7
  const int wm   = wave >> 2;  // 0..1 : A-half
  const int wn   = wave & 3;   // 0..3 : B 64-col quarter (B-half = wn>>1)
  const int mrow = lane & 15;
  const int quad = lane >> 4;

  // XCD-chunked swizzle (512 wgs, 8 XCDs, 64 consecutive per XCD).
  const int bid = blockIdx.x;
  const int swz = (bid & 7) * 64 + (bid >> 3);
  const int m0  = (swz >> 4) * BM;
  const int n0  = (swz & 15) * BN;

  // ---- staging addresses ----
  // Half-tile = 1024 chunks of 16B; chunk c: row=c>>3, phys k-slot pk=c&7,
  // logical k-chunk kc = pk ^ (row&7)  (XOR swizzle; involution).
  // Thread stages chunks c=tid (rows 0..63) and c=512+tid (rows 64..127,
  // same kc since 64%8==0). LDS dest is WAVE-UNIFORM base (HW adds lane*16).
  const int    r0  = tid >> 3;                       // 0..63
  const int    kc0 = (tid & 7) ^ (r0 & 7);
  const size_t offG = (size_t)r0 * K + kc0 * 8;
  const short* pA0 = A + (size_t)m0 * K + offG;
  const short* pA1 = pA0 + (size_t)64 * K;
  const short* pB0 = B + (size_t)n0 * K + offG;
  const short* pB1 = pB0 + (size_t)64 * K;
  const int ldsOff0 = wave << 10;            // j=0 uniform byte base
  const int ldsOff1 = 8192 + (wave << 10);   // j=1

  // ---- ds_read bases (same swizzle on read side) ----
  // row within half = (16-mult) + mrow  ->  row&7 == mrow&7.
  // kk (K 32-half) flips pk bit 2 -> byte ^ 64.
  const int pk0   = quad ^ (mrow & 7);
  const int aByte = mrow * 128 + pk0 * 16;
  const int bByte = ((wn & 1) * 64 + mrow) * 128 + pk0 * 16;

  f32x4  acc[8][4] = {};
  bf16x8 aLo[8], aHi[8], bLo[4], bHi[4];  // [idx*2+kk]

#define STG_A(bufc, h, t)                                                      \
  do {                                                                         \
    gl_lds16(pA0 + (size_t)(h) * 128 * K + (t) * BK,                           \
             (char*)&Alds[bufc][h][0] + ldsOff0);                              \
    gl_lds16(pA1 + (size_t)(h) * 128 * K + (t) * BK,                           \
             (char*)&Alds[bufc][h][0] + ldsOff1);                              \
  } while (0)
#define STG_B(bufc, h, t)                                                      \
  do {                                                                         \
    gl_lds16(pB0 + (size_t)(h) * 128 * K + (t) * BK,                           \
             (char*)&Blds[bufc][h][0] + ldsOff0);                              \
    gl_lds16(pB1 + (size_t)(h) * 128 * K + (t) * BK,                           \
             (char*)&Blds[bufc][h][0] + ldsOff1);                              \
  } while (0)

#define RD_A(p, dst, mibase)                                                   \
  do {                                                                         \
    const char* Ah = (const char*)&Alds[p][wm][0];                             \
    _Pragma("unroll") for (int mi = 0; mi < 4; ++mi) {                         \
      dst[mi * 2 + 0] = *(const bf16x8*)(Ah + ((mibase) + mi) * 2048 + aByte); \
      dst[mi * 2 + 1] =                                                        \
          *(const bf16x8*)(Ah + ((mibase) + mi) * 2048 + (aByte ^ 64));        \
    }                                                                          \
  } while (0)
#define RD_B(p, dst, nibase, cnt)                                              \
  do {                                                                         \
    const char* Bh = (const char*)&Blds[p][wn >> 1][0];                        \
    _Pragma("unroll") for (int ni = 0; ni < (cnt); ++ni) {                     \
      dst[ni * 2 + 0] = *(const bf16x8*)(Bh + ((nibase) + ni) * 2048 + bByte); \
      dst[ni * 2 + 1] =                                                        \
          *(const bf16x8*)(Bh + ((nibase) + ni) * 2048 + (bByte ^ 64));        \
    }                                                                          \
  } while (0)

#define MM(mib, nib, afr, bfr)                                                 \
  do {                                                                         \
    __builtin_amdgcn_s_setprio(1);                                             \
    _Pragma("unroll") for (int mi = 0; mi < 4; ++mi)                           \
        _Pragma("unroll") for (int ni = 0; ni < 2; ++ni)                       \
            _Pragma("unroll") for (int kk = 0; kk < 2; ++kk)                   \
                acc[(mib) + mi][(nib) + ni] =                                  \
                    __builtin_amdgcn_mfma_f32_16x16x32_bf16(                   \
                        afr[mi * 2 + kk], bfr[ni * 2 + kk],                    \
                        acc[(mib) + mi][(nib) + ni], 0, 0, 0);                 \
    __builtin_amdgcn_s_setprio(0);                                             \
  } while (0)

#define BAR __builtin_amdgcn_s_barrier()

// One K-tile: p = parity (literal), MFPREV/S1OK/S2OK literal 0/1, VM = string.
#define TILE(p, MFPREV, S1OK, S2OK, VMSTR, tS)                                 \
  do {                                                                         \
    /* P1 */                                                                   \
    RD_A(p, aLo, 0);                                                           \
    if (S1OK) STG_A(p ^ 1, 1, (tS) + 1);                                       \
    BAR;                                                                       \
    if (MFPREV) MM(4, 0, aHi, bLo);                                            \
    BAR;                                                                       \
    /* P2 */                                                                   \
    RD_B(p, bLo, 0, 2);                                                        \
    if (S1OK) STG_B(p ^ 1, 0, (tS) + 1);                                       \
    BAR;                                                                       \
    if (MFPREV) MM(4, 2, aHi, bHi);                                            \
    BAR;                                                                       \
    /* P3 (12 reads) */                                                        \
    RD_B(p, bHi, 2, 2);                                                        \
    RD_A(p, aHi, 4);                                                           \
    if (S1OK) STG_B(p ^ 1, 1, (tS) + 1);                                       \
    BAR;                                                                       \
    MM(0, 0, aLo, bLo);                                                        \
    BAR;                                                                       \
    /* P4 (0 reads) */                                                         \
    if (S2OK) STG_A(p, 0, (tS) + 2);                                           \
    BAR;                                                                       \
    MM(0, 2, aLo, bHi);                                                        \
    asm volatile("s_waitcnt vmcnt(" VMSTR ")" ::: "memory");                   \
    BAR;                                                                       \
  } while (0)

  // Prologue: fully stage tiles 0 (buf0) and 1 (buf1); ensure T0 resident.
  STG_A(0, 0, 0); STG_A(0, 1, 0); STG_B(0, 0, 0); STG_B(0, 1, 0);
  STG_A(1, 0, 1); STG_A(1, 1, 1); STG_B(1, 0, 1); STG_B(1, 1, 1);
  asm volatile("s_waitcnt vmcnt(8)" ::: "memory");
  BAR;

  // T0: no prev MFMA; T1 already staged (skip P1-P3 stages); stage A-top(2).
  TILE(0, 0, 0, 1, "2", 0);
  // T1: steady.
  TILE(1, 1, 1, 1, "2", 1);
  // Steady pairs: tiles 2..61.
#pragma unroll 1
  for (int t = 2; t < NT - 2; t += 2) {
    TILE(0, 1, 1, 1, "2", t);
    TILE(1, 1, 1, 1, "2", t + 1);
  }
  // T62: stage ht2-4(63); drain. T63: no stages.
  TILE(0, 1, 1, 0, "0", NT - 2);
  TILE(1, 1, 0, 0, "0", NT - 1);
  // Tail: Q10(63), Q11(63).
  MM(4, 0, aHi, bLo);
  MM(4, 2, aHi, bHi);

#undef TILE
#undef BAR
#undef MM
#undef RD_B
#undef RD_A
#undef STG_B
#undef STG_A

  // C-write: C/D layout col = lane&15, row = quad*4 + reg.
#pragma unroll
  for (int ni = 0; ni < 4; ++ni) {
    const int col  = n0 + wn * 64 + ni * 16 + mrow;
    const float bv = bias[col];
#pragma unroll
    for (int mi = 0; mi < 8; ++mi) {
      const int rowb = m0 + wm * 128 + mi * 16 + quad * 4;
#pragma unroll
      for (int r = 0; r < 4; ++r)
        C[(size_t)(rowb + r) * NOUT + col] = acc[mi][ni][r] + bv;
    }
  }
}

extern "C" void kernel_launch(void* const* d_in, const int* in_sizes, int n_in,
                              void* d_out, int out_size, void* d_ws, size_t ws_size,
                              hipStream_t stream) {
  const float* x    = (const float*)d_in[0];
  const float* mu_w = (const float*)d_in[1];
  const float* ls_w = (const float*)d_in[2];
  const float* mu_b = (const float*)d_in[3];
  const float* ls_b = (const float*)d_in[4];
  const float* ep_w = (const float*)d_in[5];
  const float* ep_b = (const float*)d_in[6];
  float* out = (float*)d_out;

  // Workspace layout
  char* ws = (char*)d_ws;
  short* xb   = (short*)(ws);                                  // M*K bf16   = 64 MiB
  short* wb   = (short*)(ws + (size_t)M * K * 2);              // NOUT*K bf16= 32 MiB
  float* bias = (float*)(ws + (size_t)M * K * 2 + (size_t)NOUT * K * 2);

  prep_kernel<<<XBLK + WBLK + BBLK, 256, 0, stream>>>(x, xb, mu_w, ls_w, ep_w, wb,
                                                      mu_b, ls_b, ep_b, bias);

  gemm_bt_kernel<<<(M / BM) * (NOUT / BN), 512, 0, stream>>>(xb, wb, bias, out);
}